// Round 3
// baseline (10557.934 us; speedup 1.0000x reference)
//
#include <hip/hip_runtime.h>
#include <math.h>

namespace {

constexpr int kB  = 256;   // batch
constexpr int kT  = 512;   // timesteps
constexpr int kIn = 128;   // layer0 input size
constexpr int kH  = 256;   // hidden
constexpr int kG  = 1024;  // 4*H
constexpr int kNC = 100;   // classes
constexpr int kCT = 64;    // timestep chunk
constexpr int kNCh = kT / kCT;

typedef __bf16 bf16x8 __attribute__((ext_vector_type(8)));
typedef float f32x4 __attribute__((ext_vector_type(4)));
static_assert(sizeof(bf16x8) == 16, "bf16x8 must be 4 VGPRs");

__device__ __forceinline__ float sigm(float x) {
  return __builtin_amdgcn_rcpf(1.0f + __expf(-x));       // 2 trans ops
}
__device__ __forceinline__ float tanh_f(float x) {
  const float e = __expf(-2.0f * x);                      // 2 trans ops
  return (1.0f - e) * __builtin_amdgcn_rcpf(1.0f + e);
}
__device__ __forceinline__ unsigned short f2bf(float f) {
  return __builtin_bit_cast(unsigned short, (__bf16)f);
}

// ---------------------------------------------------------------------------
// Pack W_hh [4H][H] fp32 into bf16 MFMA B-fragment order, streaming-friendly:
//   frag index f = (wv*8 + kb)*4 + g ; element = f*64*8 + l*8 + e
//   B[k][n] = Whh[n][k], n = g*256 + wv*16 + (l&15), k = kb*32 + ((l>>4)&3)*8 + e
__global__ __launch_bounds__(256) void pack_whh_frag(
    const float* __restrict__ whh, unsigned short* __restrict__ wpk) {
  const int idx = blockIdx.x * 256 + threadIdx.x;   // 0..262143
  const int e  = idx & 7;
  const int l  = (idx >> 3) & 63;
  const int g  = (idx >> 9) & 3;
  const int kb = (idx >> 11) & 7;
  const int wv = idx >> 14;
  const int n = (g << 8) | (wv << 4) | (l & 15);
  const int k = (kb << 5) | (((l >> 4) & 3) << 3) | e;
  wpk[idx] = f2bf(whh[n * kH + k]);
}

// ---------------------------------------------------------------------------
// MFMA LSTM recurrence over one chunk of kCT steps.
// Grid: 16 blocks x 1024 threads (16 waves). Block owns batch rows [b0,b0+16).
// Wave wv owns hidden units [wv*16, wv*16+16), all 4 gates (in-lane activation,
// c in registers). W_hh streamed from L2 with circular distance-2 prefetch
// (W is step-invariant, so the pipeline wraps across the step boundary).
// h (bf16) double-buffered in LDS in exact A-fragment order.
// Next step's P is loaded directly into acc after activation consumes it.
__global__ __launch_bounds__(1024, 4) void lstm_rec_mfma(
    const float* __restrict__ P,            // [kB*kCT][kG], row = b*kCT + tt
    const unsigned short* __restrict__ wpk, // packed bf16 B-fragments
    float* __restrict__ hstate,             // [kB][kH]
    float* __restrict__ cstate,             // [kB][kH]
    float* __restrict__ Hout,               // [kB*kCT][kH] or nullptr
    int first) {
  const int tid = threadIdx.x;
  const int wv = tid >> 6;
  const int l  = tid & 63;
  const int b0 = blockIdx.x << 4;
  const int jj = (wv << 4) | (l & 15);   // hidden unit owned (D column)
  const int mg = (l >> 4) << 2;          // base batch row of this lane's D rows

  __shared__ __align__(16) unsigned short abuf[2][8 * 512];  // 2 x 8KB

  const bf16x8* __restrict__ wptr =
      reinterpret_cast<const bf16x8*>(wpk) + ((size_t)wv << 11);

  // ---- state load / init; publish h into abuf[0] in fragment order ----
  f32x4 c4;
  float hnew[4];
  if (first) {
#pragma unroll
    for (int r = 0; r < 4; ++r) { c4[r] = 0.f; hnew[r] = 0.f; }
  } else {
#pragma unroll
    for (int r = 0; r < 4; ++r) {
      hnew[r] = hstate[(b0 + mg + r) * kH + jj];
      c4[r]   = cstate[(b0 + mg + r) * kH + jj];
    }
  }
  const int kb_w = jj >> 5, hi_w = (jj >> 3) & 3, e_w = jj & 7;
#pragma unroll
  for (int r = 0; r < 4; ++r)
    abuf[0][kb_w * 512 + ((mg + r) | (hi_w << 4)) * 8 + e_w] = f2bf(hnew[r]);

  // ---- W stream prologue: frags 0,1 -> bufs 0,1 ----
  bf16x8 wf[4][4];
#pragma unroll
  for (int g = 0; g < 4; ++g) wf[0][g] = wptr[(0 * 4 + g) * 64 + l];
#pragma unroll
  for (int g = 0; g < 4; ++g) wf[1][g] = wptr[(1 * 4 + g) * 64 + l];

  // ---- P for step 0 directly into acc ----
  const float* __restrict__ Pb = P + ((size_t)(b0 + mg) * kCT) * kG + jj;
  f32x4 acc[4];
#pragma unroll
  for (int g = 0; g < 4; ++g)
#pragma unroll
    for (int r = 0; r < 4; ++r)
      acc[g][r] = Pb[((size_t)r * kCT) * kG + (g << 8)];

  __syncthreads();

  for (int tt = 0; tt < kCT; ++tt) {
    const unsigned short* ab = abuf[tt & 1];
    // A-fragment lookahead (lane reads own contiguous 16B: conflict-free)
    bf16x8 a_cur = *reinterpret_cast<const bf16x8*>(ab + l * 8);
#pragma unroll
    for (int kb = 0; kb < 8; ++kb) {
      bf16x8 a_nxt;
      if (kb < 7)
        a_nxt = *reinterpret_cast<const bf16x8*>(ab + (kb + 1) * 512 + l * 8);
      // circular distance-2 W prefetch: frag (kb+2)%8 -> buf (kb+2)%4
      const int pf = (kb + 2) & 7;
#pragma unroll
      for (int g = 0; g < 4; ++g)
        wf[pf & 3][g] = wptr[(pf * 4 + g) * 64 + l];
#pragma unroll
      for (int g = 0; g < 4; ++g)
        acc[g] = __builtin_amdgcn_mfma_f32_16x16x32_bf16(a_cur, wf[kb & 3][g],
                                                         acc[g], 0, 0, 0);
      a_cur = a_nxt;
    }

    // ---- in-lane activation; lane holds i,f,g,o for rows mg..mg+3, unit jj
#pragma unroll
    for (int r = 0; r < 4; ++r) {
      const float ig = sigm(acc[0][r]);
      const float fg = sigm(acc[1][r]);
      const float gg = tanh_f(acc[2][r]);
      const float og = sigm(acc[3][r]);
      const float cc = fg * c4[r] + ig * gg;
      c4[r] = cc;
      hnew[r] = og * tanh_f(cc);
    }

    // ---- reload acc with next step's P (activation already consumed acc) ----
    const int tn = (tt + 1 < kCT) ? (tt + 1) : tt;
#pragma unroll
    for (int g = 0; g < 4; ++g)
#pragma unroll
      for (int r = 0; r < 4; ++r)
        acc[g][r] = Pb[((size_t)r * kCT + tn) * kG + (g << 8)];

    if (Hout) {
#pragma unroll
      for (int r = 0; r < 4; ++r)
        Hout[((size_t)(b0 + mg + r) * kCT + tt) * kH + jj] = hnew[r];
    }
    // ---- publish new h (bf16) into the other buffer, fragment order ----
    unsigned short* an = abuf[(tt + 1) & 1];
#pragma unroll
    for (int r = 0; r < 4; ++r)
      an[kb_w * 512 + ((mg + r) | (hi_w << 4)) * 8 + e_w] = f2bf(hnew[r]);
    __syncthreads();
  }

#pragma unroll
  for (int r = 0; r < 4; ++r) {
    hstate[(b0 + mg + r) * kH + jj] = hnew[r];
    cstate[(b0 + mg + r) * kH + jj] = c4[r];
  }
}

// ---------------------------------------------------------------------------
// P[m][n] = sum_k X[xrow(m)][k] * W[n][k] + b1[n] + b2[n]   (fp32, unchanged)
template <int K>
__global__ __launch_bounds__(256) void gemm_xw(
    const float* __restrict__ X, const float* __restrict__ W,
    const float* __restrict__ b1, const float* __restrict__ b2,
    float* __restrict__ P, int t0, int xT) {
  __shared__ float sA[64][20];
  __shared__ float sB[64][20];
  const int tid = threadIdx.x;
  const int tx = tid & 15;
  const int ty = tid >> 4;
  const int lm = tid >> 2;
  const int lk = (tid & 3) << 2;
  const int mt = blockIdx.y;
  const int nt = blockIdx.x;

  const int m_g = mt * 64 + lm;
  const int xrow = (m_g >> 6) * xT + t0 + (m_g & 63);
  const float* Arow = X + (size_t)xrow * K;
  const float* Brow = W + (size_t)(nt * 64 + lm) * K;

  float acc[4][4] = {};
  for (int kt = 0; kt < K; kt += 16) {
    const float4 av = *reinterpret_cast<const float4*>(Arow + kt + lk);
    const float4 bv = *reinterpret_cast<const float4*>(Brow + kt + lk);
    __syncthreads();
    *reinterpret_cast<float4*>(&sA[lm][lk]) = av;
    *reinterpret_cast<float4*>(&sB[lm][lk]) = bv;
    __syncthreads();
#pragma unroll
    for (int kq = 0; kq < 4; ++kq) {
      float4 a4[4], b4[4];
#pragma unroll
      for (int i = 0; i < 4; ++i)
        a4[i] = *reinterpret_cast<const float4*>(&sA[ty + 16 * i][kq * 4]);
#pragma unroll
      for (int j = 0; j < 4; ++j)
        b4[j] = *reinterpret_cast<const float4*>(&sB[tx + 16 * j][kq * 4]);
#pragma unroll
      for (int i = 0; i < 4; ++i)
#pragma unroll
        for (int j = 0; j < 4; ++j) {
          acc[i][j] += a4[i].x * b4[j].x;
          acc[i][j] += a4[i].y * b4[j].y;
          acc[i][j] += a4[i].z * b4[j].z;
          acc[i][j] += a4[i].w * b4[j].w;
        }
    }
  }
#pragma unroll
  for (int j = 0; j < 4; ++j) {
    const int n = nt * 64 + tx + 16 * j;
    const float bb = b1[n] + b2[n];
#pragma unroll
    for (int i = 0; i < 4; ++i) {
      const int m = mt * 64 + ty + 16 * i;
      P[(size_t)m * kG + n] = acc[i][j] + bb;
    }
  }
}

// out[b][n] = sum_k hlast[b][k] * fcw[n][k] + fcb[n]
__global__ __launch_bounds__(128) void fc_kernel(
    const float* __restrict__ hlast, const float* __restrict__ fcw,
    const float* __restrict__ fcb, float* __restrict__ out) {
  const int b = blockIdx.x;
  const int n = threadIdx.x;
  __shared__ float sh[kH];
  sh[n] = hlast[b * kH + n];
  sh[n + 128] = hlast[b * kH + n + 128];
  __syncthreads();
  if (n < kNC) {
    float a = fcb[n];
    const float* wrow = fcw + n * kH;
#pragma unroll 8
    for (int k = 0; k < kH; ++k) a += sh[k] * wrow[k];
    out[b * kNC + n] = a;
  }
}

}  // namespace

extern "C" void kernel_launch(void* const* d_in, const int* in_sizes, int n_in,
                              void* d_out, int out_size, void* d_ws, size_t ws_size,
                              hipStream_t stream) {
  (void)in_sizes; (void)n_in; (void)out_size; (void)ws_size;
  const float* x    = (const float*)d_in[0];
  const float* Wih0 = (const float*)d_in[1];
  const float* Whh0 = (const float*)d_in[2];
  const float* bih0 = (const float*)d_in[3];
  const float* bhh0 = (const float*)d_in[4];
  const float* Wih1 = (const float*)d_in[5];
  const float* Whh1 = (const float*)d_in[6];
  const float* bih1 = (const float*)d_in[7];
  const float* bhh1 = (const float*)d_in[8];
  const float* fcw  = (const float*)d_in[9];
  const float* fcb  = (const float*)d_in[10];
  float* out = (float*)d_out;

  // Workspace layout (~146 MB)
  char* base = (char*)d_ws;
  const size_t szP = (size_t)kB * kCT * kG * sizeof(float);  // 64 MB
  const size_t szH = (size_t)kB * kCT * kH * sizeof(float);  // 16 MB
  const size_t szS = (size_t)kB * kH * sizeof(float);        // 256 KB
  const size_t szW = (size_t)262144 * sizeof(unsigned short);// 512 KB
  float* P0  = (float*)(base);
  float* P1  = (float*)(base + szP);
  float* H0  = (float*)(base + 2 * szP);
  float* h0s = (float*)(base + 2 * szP + szH);
  float* c0s = (float*)(base + 2 * szP + szH + 1 * szS);
  float* h1s = (float*)(base + 2 * szP + szH + 2 * szS);
  float* c1s = (float*)(base + 2 * szP + szH + 3 * szS);
  unsigned short* Wpk0 = (unsigned short*)(base + 2 * szP + szH + 4 * szS);
  unsigned short* Wpk1 = (unsigned short*)(base + 2 * szP + szH + 4 * szS + szW);

  pack_whh_frag<<<dim3(1024), dim3(256), 0, stream>>>(Whh0, Wpk0);
  pack_whh_frag<<<dim3(1024), dim3(256), 0, stream>>>(Whh1, Wpk1);

  const dim3 ggrid(kG / 64, kB * kCT / 64);  // (16, 256)
  for (int ch = 0; ch < kNCh; ++ch) {
    const int first = (ch == 0) ? 1 : 0;
    gemm_xw<kIn><<<ggrid, dim3(256), 0, stream>>>(x, Wih0, bih0, bhh0, P0,
                                                  ch * kCT, kT);
    lstm_rec_mfma<<<dim3(kB / 16), dim3(1024), 0, stream>>>(P0, Wpk0, h0s, c0s,
                                                            H0, first);
    gemm_xw<kH><<<ggrid, dim3(256), 0, stream>>>(H0, Wih1, bih1, bhh1, P1,
                                                 0, kCT);
    lstm_rec_mfma<<<dim3(kB / 16), dim3(1024), 0, stream>>>(P1, Wpk1, h1s, c1s,
                                                            nullptr, first);
  }
  fc_kernel<<<dim3(kB), dim3(128), 0, stream>>>(h1s, fcw, fcb, out);
}

// Round 4
// 9034.748 us; speedup vs baseline: 1.1686x; 1.1686x over previous
//
#include <hip/hip_runtime.h>
#include <math.h>

namespace {

constexpr int kB  = 256;   // batch
constexpr int kT  = 512;   // timesteps
constexpr int kIn = 128;   // layer0 input size
constexpr int kH  = 256;   // hidden
constexpr int kG  = 1024;  // 4*H
constexpr int kNC = 100;   // classes
constexpr int kCT = 64;    // timestep chunk
constexpr int kNCh = kT / kCT;

typedef __bf16 bf16x8 __attribute__((ext_vector_type(8)));
typedef float f32x4 __attribute__((ext_vector_type(4)));
static_assert(sizeof(bf16x8) == 16, "bf16x8 must be 4 VGPRs");

__device__ __forceinline__ float sigm(float x) {
  return __builtin_amdgcn_rcpf(1.0f + __expf(-x));
}
__device__ __forceinline__ float tanh_f(float x) {
  const float e = __expf(-2.0f * x);
  return (1.0f - e) * __builtin_amdgcn_rcpf(1.0f + e);
}
__device__ __forceinline__ unsigned short f2bf(float f) {
  return __builtin_bit_cast(unsigned short, (__bf16)f);
}

// Async global->LDS, 16B per lane. Dest is wave-uniform base; HW adds lane*16.
__device__ __forceinline__ void glds16(const void* g, void* l) {
  __builtin_amdgcn_global_load_lds(
      (const __attribute__((address_space(1))) void*)g,
      (__attribute__((address_space(3))) void*)l, 16, 0, 0);
}

// ---------------------------------------------------------------------------
// Pack W_hh [4H][H] fp32 into bf16 MFMA B-fragment order (round-2 layout):
//   flat = ((((wv*4+g)*8)+kb)*64 + l)*8 + e
//   B[k][n] = Whh[n][k], n = g*256 + wv*16 + (l&15), k = kb*32 + ((l>>4)&3)*8 + e
__global__ __launch_bounds__(256) void pack_whh_frag(
    const float* __restrict__ whh, unsigned short* __restrict__ wpk) {
  const int idx = blockIdx.x * 256 + threadIdx.x;   // 0..262143
  const int e  = idx & 7;
  const int l  = (idx >> 3) & 63;
  const int kb = (idx >> 9) & 7;
  const int g  = (idx >> 12) & 3;
  const int wv = idx >> 14;
  const int n = (g << 8) | (wv << 4) | (l & 15);
  const int k = (kb << 5) | (((l >> 4) & 3) << 3) | e;
  wpk[idx] = f2bf(whh[n * kH + k]);
}

// ---------------------------------------------------------------------------
// MFMA LSTM recurrence, half-resident weights + LDS-ring streamed weights.
// Grid: 16 blocks x 1024 threads (16 waves). Block owns batch rows [b0,b0+16).
// Wave wv owns hidden units [wv*16,wv*16+16), all 4 gates (in-lane activation).
// Gates 0,1 (i,f): B-fragments persistent in registers (64 VGPR/wave).
// Gates 2,3 (g,o): streamed per step via global_load_lds into a 4-slot LDS
// ring (32KB/slot). Slot kb%4 holds slice kb; after its reads at iter kb it is
// refilled with slice (kb+4)%8 (period-8 rolling, W is step-invariant).
// __syncthreads' vmcnt(0) drain guarantees slices 0..3; iters 4..7 use
// s_waitcnt vmcnt(6) (slice kb always has >=3 younger slice-issues).
__global__ __launch_bounds__(1024, 4) void lstm_rec_mfma(
    const float* __restrict__ P,            // [kB*kCT][kG], row = b*kCT + tt
    const unsigned short* __restrict__ wpk, // packed bf16 B-fragments
    float* __restrict__ hstate,             // [kB][kH]
    float* __restrict__ cstate,             // [kB][kH]
    float* __restrict__ Hout,               // [kB*kCT][kH] or nullptr
    int first) {
  const int tid = threadIdx.x;
  const int wv = tid >> 6;
  const int l  = tid & 63;
  const int b0 = blockIdx.x << 4;
  const int jj = (wv << 4) | (l & 15);   // hidden unit owned (D column)
  const int mg = (l >> 4) << 2;          // base batch row of this lane's D rows

  __shared__ __align__(16) unsigned short ring[4][16384];  // 4 x 32KB
  __shared__ __align__(16) unsigned short abuf[2][4096];   // 2 x 8KB

  // ---- resident B-fragments: gates 0,1 (64 VGPRs) ----
  bf16x8 wr[2][8];
#pragma unroll
  for (int g = 0; g < 2; ++g)
#pragma unroll
    for (int kb = 0; kb < 8; ++kb)
      wr[g][kb] = *reinterpret_cast<const bf16x8*>(
          wpk + (size_t)(((wv * 4 + g) * 8 + kb) * 64 + l) * 8);

  // ---- state load / init; publish h into abuf[0] in fragment order ----
  f32x4 c4;
  float hnew[4];
  if (first) {
#pragma unroll
    for (int r = 0; r < 4; ++r) { c4[r] = 0.f; hnew[r] = 0.f; }
  } else {
#pragma unroll
    for (int r = 0; r < 4; ++r) {
      hnew[r] = hstate[(b0 + mg + r) * kH + jj];
      c4[r]   = cstate[(b0 + mg + r) * kH + jj];
    }
  }
  const int kb_w = jj >> 5, hi_w = (jj >> 3) & 3, e_w = jj & 7;
#pragma unroll
  for (int r = 0; r < 4; ++r)
    abuf[0][kb_w * 512 + ((mg + r) | (hi_w << 4)) * 8 + e_w] = f2bf(hnew[r]);

  // ---- prime ring slices 0..3 into slots 0..3 ----
#pragma unroll
  for (int kb = 0; kb < 4; ++kb) {
    glds16(wpk + (size_t)(((wv * 4 + 2) * 8 + kb) * 64 + l) * 8,
           &ring[kb][(wv * 2 + 0) * 512]);
    glds16(wpk + (size_t)(((wv * 4 + 3) * 8 + kb) * 64 + l) * 8,
           &ring[kb][(wv * 2 + 1) * 512]);
  }

  // ---- P prefetch for step 0 ----
  const float* __restrict__ Pb = P + ((size_t)(b0 + mg) * kCT) * kG + jj;
  f32x4 pfr[4];
#pragma unroll
  for (int g = 0; g < 4; ++g)
#pragma unroll
    for (int r = 0; r < 4; ++r)
      pfr[g][r] = Pb[((size_t)r * kCT) * kG + (g << 8)];

  __syncthreads();  // vmcnt(0) drain: ring slots 0..3 + pfr valid

  for (int tt = 0; tt < kCT; ++tt) {
    f32x4 acc[4];
#pragma unroll
    for (int g = 0; g < 4; ++g) acc[g] = pfr[g];

    const unsigned short* __restrict__ ab = abuf[tt & 1];

#pragma unroll
    for (int kb = 0; kb < 8; ++kb) {
      if (kb >= 4) asm volatile("s_waitcnt vmcnt(6)" ::: "memory");
      const unsigned short* sl = ring[kb & 3];
      const bf16x8 s2 = *reinterpret_cast<const bf16x8*>(sl + (wv * 2 + 0) * 512 + l * 8);
      const bf16x8 s3 = *reinterpret_cast<const bf16x8*>(sl + (wv * 2 + 1) * 512 + l * 8);
      const bf16x8 a  = *reinterpret_cast<const bf16x8*>(ab + kb * 512 + l * 8);
      acc[0] = __builtin_amdgcn_mfma_f32_16x16x32_bf16(a, wr[0][kb], acc[0], 0, 0, 0);
      acc[1] = __builtin_amdgcn_mfma_f32_16x16x32_bf16(a, wr[1][kb], acc[1], 0, 0, 0);
      acc[2] = __builtin_amdgcn_mfma_f32_16x16x32_bf16(a, s2, acc[2], 0, 0, 0);
      acc[3] = __builtin_amdgcn_mfma_f32_16x16x32_bf16(a, s3, acc[3], 0, 0, 0);
      // rolling refill: slot kb%4 <- slice (kb+4)%8 (next use 4 iters away)
      const int nk = (kb + 4) & 7;
      glds16(wpk + (size_t)(((wv * 4 + 2) * 8 + nk) * 64 + l) * 8,
             &ring[kb & 3][(wv * 2 + 0) * 512]);
      glds16(wpk + (size_t)(((wv * 4 + 3) * 8 + nk) * 64 + l) * 8,
             &ring[kb & 3][(wv * 2 + 1) * 512]);
      if (kb == 0) {
        // prefetch next step's P (7 iters + barrier of latency cover)
        const int tn = (tt + 1 < kCT) ? (tt + 1) : tt;
#pragma unroll
        for (int g = 0; g < 4; ++g)
#pragma unroll
          for (int r = 0; r < 4; ++r)
            pfr[g][r] = Pb[((size_t)r * kCT + tn) * kG + (g << 8)];
      }
    }

    // ---- in-lane activation: lane holds i,f,g,o for rows mg..mg+3, unit jj
#pragma unroll
    for (int r = 0; r < 4; ++r) {
      const float ig = sigm(acc[0][r]);
      const float fg = sigm(acc[1][r]);
      const float gg = tanh_f(acc[2][r]);
      const float og = sigm(acc[3][r]);
      const float cc = fg * c4[r] + ig * gg;
      c4[r] = cc;
      hnew[r] = og * tanh_f(cc);
    }

    if (Hout) {
#pragma unroll
      for (int r = 0; r < 4; ++r)
        Hout[((size_t)(b0 + mg + r) * kCT + tt) * kH + jj] = hnew[r];
    }
    // ---- publish new h (bf16) into the other buffer, fragment order ----
    unsigned short* an = abuf[(tt + 1) & 1];
#pragma unroll
    for (int r = 0; r < 4; ++r)
      an[kb_w * 512 + ((mg + r) | (hi_w << 4)) * 8 + e_w] = f2bf(hnew[r]);
    __syncthreads();  // also drains glds refills + pfr (vmcnt(0))
  }

#pragma unroll
  for (int r = 0; r < 4; ++r) {
    hstate[(b0 + mg + r) * kH + jj] = hnew[r];
    cstate[(b0 + mg + r) * kH + jj] = c4[r];
  }
}

// ---------------------------------------------------------------------------
// P[m][n] = sum_k X[xrow(m)][k] * W[n][k] + b1[n] + b2[n]   (fp32, unchanged)
template <int K>
__global__ __launch_bounds__(256) void gemm_xw(
    const float* __restrict__ X, const float* __restrict__ W,
    const float* __restrict__ b1, const float* __restrict__ b2,
    float* __restrict__ P, int t0, int xT) {
  __shared__ float sA[64][20];
  __shared__ float sB[64][20];
  const int tid = threadIdx.x;
  const int tx = tid & 15;
  const int ty = tid >> 4;
  const int lm = tid >> 2;
  const int lk = (tid & 3) << 2;
  const int mt = blockIdx.y;
  const int nt = blockIdx.x;

  const int m_g = mt * 64 + lm;
  const int xrow = (m_g >> 6) * xT + t0 + (m_g & 63);
  const float* Arow = X + (size_t)xrow * K;
  const float* Brow = W + (size_t)(nt * 64 + lm) * K;

  float acc[4][4] = {};
  for (int kt = 0; kt < K; kt += 16) {
    const float4 av = *reinterpret_cast<const float4*>(Arow + kt + lk);
    const float4 bv = *reinterpret_cast<const float4*>(Brow + kt + lk);
    __syncthreads();
    *reinterpret_cast<float4*>(&sA[lm][lk]) = av;
    *reinterpret_cast<float4*>(&sB[lm][lk]) = bv;
    __syncthreads();
#pragma unroll
    for (int kq = 0; kq < 4; ++kq) {
      float4 a4[4], b4[4];
#pragma unroll
      for (int i = 0; i < 4; ++i)
        a4[i] = *reinterpret_cast<const float4*>(&sA[ty + 16 * i][kq * 4]);
#pragma unroll
      for (int j = 0; j < 4; ++j)
        b4[j] = *reinterpret_cast<const float4*>(&sB[tx + 16 * j][kq * 4]);
#pragma unroll
      for (int i = 0; i < 4; ++i)
#pragma unroll
        for (int j = 0; j < 4; ++j) {
          acc[i][j] += a4[i].x * b4[j].x;
          acc[i][j] += a4[i].y * b4[j].y;
          acc[i][j] += a4[i].z * b4[j].z;
          acc[i][j] += a4[i].w * b4[j].w;
        }
    }
  }
#pragma unroll
  for (int j = 0; j < 4; ++j) {
    const int n = nt * 64 + tx + 16 * j;
    const float bb = b1[n] + b2[n];
#pragma unroll
    for (int i = 0; i < 4; ++i) {
      const int m = mt * 64 + ty + 16 * i;
      P[(size_t)m * kG + n] = acc[i][j] + bb;
    }
  }
}

// out[b][n] = sum_k hlast[b][k] * fcw[n][k] + fcb[n]
__global__ __launch_bounds__(128) void fc_kernel(
    const float* __restrict__ hlast, const float* __restrict__ fcw,
    const float* __restrict__ fcb, float* __restrict__ out) {
  const int b = blockIdx.x;
  const int n = threadIdx.x;
  __shared__ float sh[kH];
  sh[n] = hlast[b * kH + n];
  sh[n + 128] = hlast[b * kH + n + 128];
  __syncthreads();
  if (n < kNC) {
    float a = fcb[n];
    const float* wrow = fcw + n * kH;
#pragma unroll 8
    for (int k = 0; k < kH; ++k) a += sh[k] * wrow[k];
    out[b * kNC + n] = a;
  }
}

}  // namespace

extern "C" void kernel_launch(void* const* d_in, const int* in_sizes, int n_in,
                              void* d_out, int out_size, void* d_ws, size_t ws_size,
                              hipStream_t stream) {
  (void)in_sizes; (void)n_in; (void)out_size; (void)ws_size;
  const float* x    = (const float*)d_in[0];
  const float* Wih0 = (const float*)d_in[1];
  const float* Whh0 = (const float*)d_in[2];
  const float* bih0 = (const float*)d_in[3];
  const float* bhh0 = (const float*)d_in[4];
  const float* Wih1 = (const float*)d_in[5];
  const float* Whh1 = (const float*)d_in[6];
  const float* bih1 = (const float*)d_in[7];
  const float* bhh1 = (const float*)d_in[8];
  const float* fcw  = (const float*)d_in[9];
  const float* fcb  = (const float*)d_in[10];
  float* out = (float*)d_out;

  // Workspace layout (~146 MB)
  char* base = (char*)d_ws;
  const size_t szP = (size_t)kB * kCT * kG * sizeof(float);  // 64 MB
  const size_t szH = (size_t)kB * kCT * kH * sizeof(float);  // 16 MB
  const size_t szS = (size_t)kB * kH * sizeof(float);        // 256 KB
  const size_t szW = (size_t)262144 * sizeof(unsigned short);// 512 KB
  float* P0  = (float*)(base);
  float* P1  = (float*)(base + szP);
  float* H0  = (float*)(base + 2 * szP);
  float* h0s = (float*)(base + 2 * szP + szH);
  float* c0s = (float*)(base + 2 * szP + szH + 1 * szS);
  float* h1s = (float*)(base + 2 * szP + szH + 2 * szS);
  float* c1s = (float*)(base + 2 * szP + szH + 3 * szS);
  unsigned short* Wpk0 = (unsigned short*)(base + 2 * szP + szH + 4 * szS);
  unsigned short* Wpk1 = (unsigned short*)(base + 2 * szP + szH + 4 * szS + szW);

  pack_whh_frag<<<dim3(1024), dim3(256), 0, stream>>>(Whh0, Wpk0);
  pack_whh_frag<<<dim3(1024), dim3(256), 0, stream>>>(Whh1, Wpk1);

  const dim3 ggrid(kG / 64, kB * kCT / 64);  // (16, 256)
  for (int ch = 0; ch < kNCh; ++ch) {
    const int first = (ch == 0) ? 1 : 0;
    gemm_xw<kIn><<<ggrid, dim3(256), 0, stream>>>(x, Wih0, bih0, bhh0, P0,
                                                  ch * kCT, kT);
    lstm_rec_mfma<<<dim3(kB / 16), dim3(1024), 0, stream>>>(P0, Wpk0, h0s, c0s,
                                                            H0, first);
    gemm_xw<kH><<<ggrid, dim3(256), 0, stream>>>(H0, Wih1, bih1, bhh1, P1,
                                                 0, kCT);
    lstm_rec_mfma<<<dim3(kB / 16), dim3(1024), 0, stream>>>(P1, Wpk1, h1s, c1s,
                                                            nullptr, first);
  }
  fc_kernel<<<dim3(kB), dim3(128), 0, stream>>>(h1s, fcw, fcb, out);
}